// Round 1
// baseline (155.642 us; speedup 1.0000x reference)
//
#include <hip/hip_runtime.h>
#include <hip/hip_bf16.h>

#define B_TOT 16384
#define C_CH  64
#define F_IN  128
#define H_HID 128
#define BM    128

using f32x4  = __attribute__((ext_vector_type(4))) float;
using bf16x8 = __attribute__((ext_vector_type(8))) short;

__device__ inline unsigned pack2(float a, float b) {
    unsigned short lo = __builtin_bit_cast(unsigned short, __float2bfloat16(a));
    unsigned short hi = __builtin_bit_cast(unsigned short, __float2bfloat16(b));
    return (unsigned)lo | ((unsigned)hi << 16);
}

__global__ __launch_bounds__(256, 2)
void fused_mlp_kernel(const float* __restrict__ X,
                      const float* __restrict__ W1,
                      const float* __restrict__ b1,
                      const float* __restrict__ W2,
                      const float* __restrict__ b2,
                      float* __restrict__ out)
{
    // bf16 tiles, XOR-swizzled: byte offset within a 256B row ^= (row&7)<<4
    __shared__ short Xs[BM * F_IN];     // [row][k]
    __shared__ short Ws[H_HID * F_IN];  // [n][k]  (W1 transposed)

    const int t    = threadIdx.x;
    const int lane = t & 63;
    const int wave = t >> 6;
    const int c    = blockIdx.y;          // channel (slow-varying -> W1_c stays L2 hot)
    const int m0   = blockIdx.x * BM;

    char* xs = reinterpret_cast<char*>(Xs);
    char* ws = reinterpret_cast<char*>(Ws);

    // ---- stage X tile: 128 rows x 128 fp32 -> bf16, coalesced float4 reads ----
    {
        const float* xbase = X + ((size_t)m0 * C_CH + c) * F_IN;
        #pragma unroll
        for (int i = 0; i < 16; ++i) {
            int flat  = i * 256 + t;      // 0..4095
            int row   = flat >> 5;        // 0..127
            int chunk = flat & 31;        // float4 index within row
            float4 v = *reinterpret_cast<const float4*>(
                xbase + (size_t)row * (C_CH * F_IN) + chunk * 4);
            uint2 p;
            p.x = pack2(v.x, v.y);
            p.y = pack2(v.z, v.w);
            int byte = (chunk * 8) ^ ((row & 7) << 4);
            *reinterpret_cast<uint2*>(xs + row * 256 + byte) = p;
        }
    }

    // ---- stage W1_c transposed to [n][k]: coalesced scalar reads along n ----
    {
        const int n  = t & 127;
        const int kh = (t >> 7) * 64;     // k half: 0 or 64
        const float* wbase = W1 + (size_t)c * F_IN * H_HID + n;
        #pragma unroll
        for (int kk = 0; kk < 64; kk += 8) {
            float f[8];
            #pragma unroll
            for (int j = 0; j < 8; ++j)
                f[j] = wbase[(size_t)(kh + kk + j) * H_HID];
            uint4 p;
            p.x = pack2(f[0], f[1]);
            p.y = pack2(f[2], f[3]);
            p.z = pack2(f[4], f[5]);
            p.w = pack2(f[6], f[7]);
            int byte = ((kh + kk) * 2) ^ ((n & 7) << 4);
            *reinterpret_cast<uint4*>(ws + n * 256 + byte) = p;
        }
    }

    __syncthreads();

    // ---- MFMA: wave owns rows [wave*32, wave*32+32), all 128 cols ----
    f32x4 acc[2][8];
    #pragma unroll
    for (int mf = 0; mf < 2; ++mf)
        #pragma unroll
        for (int nf = 0; nf < 8; ++nf)
            acc[mf][nf] = f32x4{0.f, 0.f, 0.f, 0.f};

    const int l15 = lane & 15;
    const int lg  = lane >> 4;            // 0..3

    #pragma unroll
    for (int ks = 0; ks < 4; ++ks) {
        const int kbyte = ks * 64 + lg * 16;   // 8 bf16 per lane, contiguous k
        bf16x8 a[2], b[8];
        #pragma unroll
        for (int mf = 0; mf < 2; ++mf) {
            int row = wave * 32 + mf * 16 + l15;
            a[mf] = *reinterpret_cast<const bf16x8*>(
                xs + row * 256 + (kbyte ^ ((row & 7) << 4)));
        }
        #pragma unroll
        for (int nf = 0; nf < 8; ++nf) {
            int n = nf * 16 + l15;
            b[nf] = *reinterpret_cast<const bf16x8*>(
                ws + n * 256 + (kbyte ^ ((n & 7) << 4)));
        }
        #pragma unroll
        for (int mf = 0; mf < 2; ++mf)
            #pragma unroll
            for (int nf = 0; nf < 8; ++nf)
                acc[mf][nf] = __builtin_amdgcn_mfma_f32_16x16x32_bf16(
                    a[mf], b[nf], acc[mf][nf], 0, 0, 0);
    }

    // ---- epilogue: relu(+b1), dot W2, 16-lane row reduce, atomicAdd ----
    float w2v[8], b1v[8];
    #pragma unroll
    for (int nf = 0; nf < 8; ++nf) {
        w2v[nf] = W2[c * H_HID + nf * 16 + l15];
        b1v[nf] = b1[c * H_HID + nf * 16 + l15];
    }
    const float b2c = b2[c];

    #pragma unroll
    for (int mf = 0; mf < 2; ++mf) {
        float part[4] = {0.f, 0.f, 0.f, 0.f};
        // acc element j: row = lg*4 + j (within 16x16 frag), col = l15
        #pragma unroll
        for (int nf = 0; nf < 8; ++nf)
            #pragma unroll
            for (int j = 0; j < 4; ++j)
                part[j] += fmaxf(acc[mf][nf][j] + b1v[nf], 0.f) * w2v[nf];
        // reduce over the 16 lanes holding cols 0..15 of the same rows
        #pragma unroll
        for (int off = 8; off >= 1; off >>= 1)
            #pragma unroll
            for (int j = 0; j < 4; ++j)
                part[j] += __shfl_xor(part[j], off, 64);
        if (l15 == 0) {
            int row = m0 + wave * 32 + mf * 16 + lg * 4;
            #pragma unroll
            for (int j = 0; j < 4; ++j)
                atomicAdd(&out[row + j], part[j] + b2c);
        }
    }
}

extern "C" void kernel_launch(void* const* d_in, const int* in_sizes, int n_in,
                              void* d_out, int out_size, void* d_ws, size_t ws_size,
                              hipStream_t stream) {
    const float* X  = (const float*)d_in[0];   // [B, C, F]
    const float* W1 = (const float*)d_in[1];   // [C, F, H]
    const float* b1 = (const float*)d_in[2];   // [C, H]
    const float* W2 = (const float*)d_in[3];   // [C, H]
    const float* b2 = (const float*)d_in[4];   // [C]
    float* out = (float*)d_out;                // [B]

    // atomics accumulate into out -> must zero it every call (d_out is poisoned)
    hipMemsetAsync(out, 0, (size_t)out_size * sizeof(float), stream);

    dim3 grid(B_TOT / BM, C_CH);
    fused_mlp_kernel<<<grid, dim3(256), 0, stream>>>(X, W1, b1, W2, b2, out);
}

// Round 2
// 134.447 us; speedup vs baseline: 1.1576x; 1.1576x over previous
//
#include <hip/hip_runtime.h>
#include <hip/hip_bf16.h>

#define B_TOT 16384
#define C_CH  64
#define F_IN  128
#define H_HID 128
#define ROWS  512      // rows per block
#define NCHUNK 4       // chunks per wave; 4 waves * 4 chunks * 32 rows = 512

using f32x4  = __attribute__((ext_vector_type(4))) float;
using bf16x8 = __attribute__((ext_vector_type(8))) short;

__device__ inline unsigned pack2(float a, float b) {
    unsigned short lo = __builtin_bit_cast(unsigned short, __float2bfloat16(a));
    unsigned short hi = __builtin_bit_cast(unsigned short, __float2bfloat16(b));
    return (unsigned)lo | ((unsigned)hi << 16);
}

__global__ __launch_bounds__(256, 2)
void fused_mlp_kernel(const float* __restrict__ X,
                      const float* __restrict__ W1,
                      const float* __restrict__ b1,
                      const float* __restrict__ W2,
                      const float* __restrict__ b2,
                      float* __restrict__ out)
{
    // Only W1 is staged (32 KB bf16, [n][k], XOR-swizzled). X goes straight
    // global->reg: X rows have no cross-wave reuse, so LDS staging of X is
    // pure overhead (r1 lesson).
    __shared__ short Ws[H_HID * F_IN];

    const int t    = threadIdx.x;
    const int lane = t & 63;
    const int wave = t >> 6;
    const int c    = blockIdx.y;
    const int m0   = blockIdx.x * ROWS;

    char* ws = reinterpret_cast<char*>(Ws);

    // ---- stage W1_c transposed to [n][k]: coalesced along n, once per 512 rows ----
    {
        const int n  = t & 127;
        const int kh = (t >> 7) * 64;     // k half: 0 or 64
        const float* wbase = W1 + (size_t)c * F_IN * H_HID + n;
        #pragma unroll
        for (int kk = 0; kk < 64; kk += 8) {
            float f[8];
            #pragma unroll
            for (int j = 0; j < 8; ++j)
                f[j] = wbase[(size_t)(kh + kk + j) * H_HID];
            uint4 p;
            p.x = pack2(f[0], f[1]);
            p.y = pack2(f[2], f[3]);
            p.z = pack2(f[4], f[5]);
            p.w = pack2(f[6], f[7]);
            int byte = ((kh + kk) * 2) ^ ((n & 7) << 4);
            *reinterpret_cast<uint4*>(ws + n * 256 + byte) = p;
        }
    }

    const int l15 = lane & 15;
    const int lg  = lane >> 4;            // 0..3

    // per-thread epilogue constants (col = nf*16 + l15)
    float w2v[8], b1v[8];
    #pragma unroll
    for (int nf = 0; nf < 8; ++nf) {
        w2v[nf] = W2[c * H_HID + nf * 16 + l15];
        b1v[nf] = b1[c * H_HID + nf * 16 + l15];
    }
    const float b2c = b2[c];

    __syncthreads();   // Ws ready

    // ---- main loop: each wave streams 4 chunks of 32 rows, no barriers ----
    #pragma unroll 1
    for (int ch = 0; ch < NCHUNK; ++ch) {
        const int rbase = m0 + (ch * 4 + wave) * 32;

        // issue all 16 global loads for this chunk up front (16 KB/wave in flight)
        float4 raw[8][2];
        #pragma unroll
        for (int mf = 0; mf < 2; ++mf) {
            const float* xb = X + ((size_t)(rbase + mf * 16 + l15) * C_CH + c) * F_IN + lg * 8;
            #pragma unroll
            for (int ks = 0; ks < 4; ++ks) {
                raw[mf * 4 + ks][0] = *reinterpret_cast<const float4*>(xb + ks * 32);
                raw[mf * 4 + ks][1] = *reinterpret_cast<const float4*>(xb + ks * 32 + 4);
            }
        }

        f32x4 acc[2][8];
        #pragma unroll
        for (int mf = 0; mf < 2; ++mf)
            #pragma unroll
            for (int nf = 0; nf < 8; ++nf)
                acc[mf][nf] = f32x4{0.f, 0.f, 0.f, 0.f};

        #pragma unroll
        for (int ks = 0; ks < 4; ++ks) {
            const int kbyte = ks * 64 + lg * 16;
            bf16x8 b[8];
            #pragma unroll
            for (int nf = 0; nf < 8; ++nf) {
                int n = nf * 16 + l15;
                b[nf] = *reinterpret_cast<const bf16x8*>(
                    ws + n * 256 + (kbyte ^ ((n & 7) << 4)));
            }
            #pragma unroll
            for (int mf = 0; mf < 2; ++mf) {
                float4 r0 = raw[mf * 4 + ks][0];
                float4 r1 = raw[mf * 4 + ks][1];
                uint4 pa;
                pa.x = pack2(r0.x, r0.y);
                pa.y = pack2(r0.z, r0.w);
                pa.z = pack2(r1.x, r1.y);
                pa.w = pack2(r1.z, r1.w);
                bf16x8 a = __builtin_bit_cast(bf16x8, pa);
                #pragma unroll
                for (int nf = 0; nf < 8; ++nf)
                    acc[mf][nf] = __builtin_amdgcn_mfma_f32_16x16x32_bf16(
                        a, b[nf], acc[mf][nf], 0, 0, 0);
            }
        }

        // ---- epilogue: relu(+b1), dot W2, 16-lane col reduce, atomicAdd ----
        #pragma unroll
        for (int mf = 0; mf < 2; ++mf) {
            float part[4] = {0.f, 0.f, 0.f, 0.f};
            #pragma unroll
            for (int nf = 0; nf < 8; ++nf)
                #pragma unroll
                for (int j = 0; j < 4; ++j)
                    part[j] += fmaxf(acc[mf][nf][j] + b1v[nf], 0.f) * w2v[nf];
            #pragma unroll
            for (int off = 8; off >= 1; off >>= 1)
                #pragma unroll
                for (int j = 0; j < 4; ++j)
                    part[j] += __shfl_xor(part[j], off, 64);
            if (l15 == 0) {
                int row = rbase + mf * 16 + lg * 4;
                #pragma unroll
                for (int j = 0; j < 4; ++j)
                    atomicAdd(&out[row + j], part[j] + b2c);
            }
        }
    }
}

extern "C" void kernel_launch(void* const* d_in, const int* in_sizes, int n_in,
                              void* d_out, int out_size, void* d_ws, size_t ws_size,
                              hipStream_t stream) {
    const float* X  = (const float*)d_in[0];   // [B, C, F]
    const float* W1 = (const float*)d_in[1];   // [C, F, H]
    const float* b1 = (const float*)d_in[2];   // [C, H]
    const float* W2 = (const float*)d_in[3];   // [C, H]
    const float* b2 = (const float*)d_in[4];   // [C]
    float* out = (float*)d_out;                // [B]

    // atomics accumulate into out -> must zero it every call (d_out is poisoned)
    hipMemsetAsync(out, 0, (size_t)out_size * sizeof(float), stream);

    dim3 grid(B_TOT / ROWS, C_CH);
    fused_mlp_kernel<<<grid, dim3(256), 0, stream>>>(X, W1, b1, W2, b2, out);
}

// Round 3
// 118.482 us; speedup vs baseline: 1.3136x; 1.1347x over previous
//
#include <hip/hip_runtime.h>
#include <hip/hip_bf16.h>

#define B_TOT 16384
#define C_CH  64
#define F_IN  128
#define H_HID 128
#define ROWS  512      // rows per block; 4 waves x 8 sub-chunks x 16 rows

using f32x4  = __attribute__((ext_vector_type(4))) float;
using bf16x8 = __attribute__((ext_vector_type(8))) short;

__device__ inline unsigned pack2(float a, float b) {
    unsigned short lo = __builtin_bit_cast(unsigned short, __float2bfloat16(a));
    unsigned short hi = __builtin_bit_cast(unsigned short, __float2bfloat16(b));
    return (unsigned)lo | ((unsigned)hi << 16);
}

// issue the 8 float4 loads for one 16-row sub-chunk (kept in flight ~8KB/wave)
__device__ inline void load_sub(const float* __restrict__ X, int rbase, int c,
                                int l15, int lg, float4 (&r)[8]) {
    const float* xb = X + ((size_t)(rbase + l15) * C_CH + c) * F_IN + lg * 8;
    #pragma unroll
    for (int ks = 0; ks < 4; ++ks) {
        r[ks * 2]     = *reinterpret_cast<const float4*>(xb + ks * 32);
        r[ks * 2 + 1] = *reinterpret_cast<const float4*>(xb + ks * 32 + 4);
    }
}

__device__ inline void compute_sub(const char* ws, const float4 (&r)[8],
                                   const float (&w2v)[8], const float (&b1v)[8],
                                   float b2c, int rbase, int l15, int lg,
                                   float* __restrict__ out)
{
    f32x4 acc[8];
    #pragma unroll
    for (int nf = 0; nf < 8; ++nf) acc[nf] = f32x4{0.f, 0.f, 0.f, 0.f};

    #pragma unroll
    for (int ks = 0; ks < 4; ++ks) {
        const int kbyte = ks * 64 + lg * 16;
        float4 r0 = r[ks * 2], r1 = r[ks * 2 + 1];
        uint4 pa;
        pa.x = pack2(r0.x, r0.y);
        pa.y = pack2(r0.z, r0.w);
        pa.z = pack2(r1.x, r1.y);
        pa.w = pack2(r1.z, r1.w);
        bf16x8 a = __builtin_bit_cast(bf16x8, pa);
        #pragma unroll
        for (int nf = 0; nf < 8; ++nf) {
            int n = nf * 16 + l15;
            bf16x8 b = *reinterpret_cast<const bf16x8*>(
                ws + n * 256 + (kbyte ^ ((n & 7) << 4)));
            acc[nf] = __builtin_amdgcn_mfma_f32_16x16x32_bf16(a, b, acc[nf], 0, 0, 0);
        }
    }

    // relu(+b1), dot W2, 16-lane col reduce, one atomic per row
    float part[4] = {0.f, 0.f, 0.f, 0.f};
    #pragma unroll
    for (int nf = 0; nf < 8; ++nf)
        #pragma unroll
        for (int j = 0; j < 4; ++j)
            part[j] += fmaxf(acc[nf][j] + b1v[nf], 0.f) * w2v[nf];
    #pragma unroll
    for (int off = 8; off >= 1; off >>= 1)
        #pragma unroll
        for (int j = 0; j < 4; ++j)
            part[j] += __shfl_xor(part[j], off, 64);
    if (l15 == 0) {
        int row = rbase + lg * 4;
        #pragma unroll
        for (int j = 0; j < 4; ++j)
            atomicAdd(&out[row + j], part[j] + b2c);
    }
}

__global__ __launch_bounds__(256, 2)
void fused_mlp_kernel(const float* __restrict__ X,
                      const float* __restrict__ W1,
                      const float* __restrict__ b1,
                      const float* __restrict__ W2,
                      const float* __restrict__ b2,
                      float* __restrict__ out)
{
    __shared__ short Ws[H_HID * F_IN];   // W1_c bf16 [n][k], XOR-swizzled

    const int t    = threadIdx.x;
    const int lane = t & 63;
    const int wave = t >> 6;
    // channel-major grid: co-resident blocks cover ALL channels of consecutive
    // rowtiles -> near-sequential DRAM stream; XCD = c%8 -> W1_c L2-pinned.
    const int c    = blockIdx.x;
    const int m0   = blockIdx.y * ROWS;

    char* ws = reinterpret_cast<char*>(Ws);

    // ---- stage W1_c transposed to [n][k]: coalesced along n ----
    {
        const int n  = t & 127;
        const int kh = (t >> 7) * 64;
        const float* wbase = W1 + (size_t)c * F_IN * H_HID + n;
        #pragma unroll
        for (int kk = 0; kk < 64; kk += 8) {
            float f[8];
            #pragma unroll
            for (int j = 0; j < 8; ++j)
                f[j] = wbase[(size_t)(kh + kk + j) * H_HID];
            uint4 p;
            p.x = pack2(f[0], f[1]);
            p.y = pack2(f[2], f[3]);
            p.z = pack2(f[4], f[5]);
            p.w = pack2(f[6], f[7]);
            int byte = ((kh + kk) * 2) ^ ((n & 7) << 4);
            *reinterpret_cast<uint4*>(ws + n * 256 + byte) = p;
        }
    }

    const int l15 = lane & 15;
    const int lg  = lane >> 4;

    float w2v[8], b1v[8];
    #pragma unroll
    for (int nf = 0; nf < 8; ++nf) {
        w2v[nf] = W2[c * H_HID + nf * 16 + l15];
        b1v[nf] = b1[c * H_HID + nf * 16 + l15];
    }
    const float b2c = b2[c];

    __syncthreads();

    // ---- software-pipelined stream: 8 sub-chunks of 16 rows, rA/rB ping-pong ----
    float4 rA[8], rB[8];
    load_sub(X, m0 + wave * 16, c, l15, lg, rA);

    #pragma unroll 1
    for (int sc = 0; sc < 8; sc += 2) {
        const int rbA = m0 + (sc * 4 + wave) * 16;
        const int rbB = m0 + ((sc + 1) * 4 + wave) * 16;
        load_sub(X, rbB, c, l15, lg, rB);                 // prefetch sc+1
        compute_sub(ws, rA, w2v, b1v, b2c, rbA, l15, lg, out);
        if (sc + 2 < 8)
            load_sub(X, m0 + ((sc + 2) * 4 + wave) * 16, c, l15, lg, rA); // prefetch sc+2
        compute_sub(ws, rB, w2v, b1v, b2c, rbB, l15, lg, out);
    }
}

extern "C" void kernel_launch(void* const* d_in, const int* in_sizes, int n_in,
                              void* d_out, int out_size, void* d_ws, size_t ws_size,
                              hipStream_t stream) {
    const float* X  = (const float*)d_in[0];   // [B, C, F]
    const float* W1 = (const float*)d_in[1];   // [C, F, H]
    const float* b1 = (const float*)d_in[2];   // [C, H]
    const float* W2 = (const float*)d_in[3];   // [C, H]
    const float* b2 = (const float*)d_in[4];   // [C]
    float* out = (float*)d_out;                // [B]

    // atomics accumulate into out -> must zero it every call (d_out is poisoned)
    hipMemsetAsync(out, 0, (size_t)out_size * sizeof(float), stream);

    dim3 grid(C_CH, B_TOT / ROWS);   // channel-major
    fused_mlp_kernel<<<grid, dim3(256), 0, stream>>>(X, W1, b1, W2, b2, out);
}